// Round 5
// baseline (90.330 us; speedup 1.0000x reference)
//
#include <hip/hip_runtime.h>

#define D_CLAMP2 100.0f   // D_CLAMP^2
#define EPS_F    1e-4f
#define Z_F      10.0f

// ---------------------------------------------------------------------------
// Pass 1: interleave atom positions into 32 B rows for single-line uniform
// loads:  y[b*N+j] = {xp0,xp1,xp2,xt0,xt1,xt2,0,0}.  Also zeroes out[].
// ---------------------------------------------------------------------------
__global__ __launch_bounds__(256) void fape_pre(
    const float* __restrict__ pred_pos, const float* __restrict__ true_pos,
    float* __restrict__ y, float* __restrict__ out, int total, int nb)
{
    const int f = blockIdx.x * 256 + threadIdx.x;
    if (f < nb) out[f] = 0.0f;
    if (f >= total) return;
    const float* p = pred_pos + (size_t)f * 3;
    const float* t = true_pos + (size_t)f * 3;
    float* Y = y + (size_t)f * 8;
    Y[0] = p[0]; Y[1] = p[1]; Y[2] = p[2];
    Y[3] = t[0]; Y[4] = t[1]; Y[5] = t[2];
    Y[6] = 0.0f; Y[7] = 0.0f;
}

// ---------------------------------------------------------------------------
// Pass 2: LANE OWNS FRAME i. Its 21 constants (Rp, Rt, c) sit in VGPRs for the
// whole kernel. The j-loop reads ONE wave-uniform 32 B row per iteration
// (1 cache line, L1-resident 2 KB slice) and issues 24 VALU instrs per pair:
// 18 FMA (Rt negation folded into -src modifiers) + 3 norm FMA + min + sqrt
// + acc. No per-lane memory traffic in the hot loop at all.
// ---------------------------------------------------------------------------
__global__ __launch_bounds__(256) void fape_main(
    const float* __restrict__ pred_rot,   // [B,N,3,3]
    const float* __restrict__ pred_trans, // [B,N,3]
    const float* __restrict__ true_rot,   // [B,N,3,3]
    const float* __restrict__ true_trans, // [B,N,3]
    const float4* __restrict__ y,         // [B*N, 2] float4 rows
    float* __restrict__ out,              // [B]
    int N, int jChunks)
{
    const int jc  = blockIdx.x % jChunks;   // which 64-wide j slice
    const int fcb = blockIdx.x / jChunks;   // which 256-wide i slice (in batch)
    const int b   = blockIdx.y;

    const int i   = fcb * 256 + threadIdx.x;        // this lane's frame
    const float wF = (i < N) ? 1.0f : 0.0f;
    const int iv  = i < N ? i : N - 1;
    const size_t fi = (size_t)b * N + iv;

    // Per-lane frame constants -> VGPRs (loaded once; one-time scattered loads).
    float rp[9], rt[9];
    const float* Rp = pred_rot + fi * 9;
    const float* Rt = true_rot + fi * 9;
#pragma unroll
    for (int q = 0; q < 9; ++q) { rp[q] = Rp[q]; rt[q] = Rt[q]; }
    const float* tpv = pred_trans + fi * 3;
    const float* ttv = true_trans + fi * 3;
    const float tp0 = tpv[0], tp1 = tpv[1], tp2 = tpv[2];
    const float tt0 = ttv[0], tt1 = ttv[1], tt2 = ttv[2];
    // c[o] = Rt^T tt - Rp^T tp   (so d = Rp^T xp - Rt^T xt + c)
    float cn[3];
#pragma unroll
    for (int o = 0; o < 3; ++o) {
        cn[o] = (rt[0+o]*tt0 + rt[3+o]*tt1 + rt[6+o]*tt2)
              - (rp[0+o]*tp0 + rp[3+o]*tp1 + rp[6+o]*tp2);
    }

    const int j0   = jc * 64;
    const int jEnd = (N - j0) < 64 ? (N - j0) : 64;
    const float4* Y = y + ((size_t)b * N + j0) * 2;

    float sum = 0.0f;
#pragma unroll 4
    for (int jj = 0; jj < jEnd; ++jj) {
        // Wave-uniform row: 1 cache line. a = xp_j, t = xt_j.
        const float4 ya = Y[2*jj + 0];
        const float4 yb = Y[2*jj + 1];
        const float a0 = ya.x, a1 = ya.y, a2 = ya.z;
        const float b0 = ya.w, b1 = yb.x, b2 = yb.y;

        const float d0 = fmaf(rp[0], a0, fmaf(rp[3], a1, fmaf(rp[6], a2,
                         fmaf(-rt[0], b0, fmaf(-rt[3], b1, fmaf(-rt[6], b2, cn[0]))))));
        const float d1 = fmaf(rp[1], a0, fmaf(rp[4], a1, fmaf(rp[7], a2,
                         fmaf(-rt[1], b0, fmaf(-rt[4], b1, fmaf(-rt[7], b2, cn[1]))))));
        const float d2 = fmaf(rp[2], a0, fmaf(rp[5], a1, fmaf(rp[8], a2,
                         fmaf(-rt[2], b0, fmaf(-rt[5], b1, fmaf(-rt[8], b2, cn[2]))))));
        const float s2 = fmaf(d0, d0, fmaf(d1, d1, fmaf(d2, d2, EPS_F)));
        // min(sqrt(x),10) == sqrt(min(x,100)) exactly (sqrt monotone, sqrt(100)=10)
        sum += __builtin_amdgcn_sqrtf(fminf(s2, D_CLAMP2));
    }
    sum *= wF;   // invalid (clamped) frames contribute 0; values were finite

    // Wave (64-lane) shuffle reduction; all lanes in this block share batch b.
#pragma unroll
    for (int off = 32; off > 0; off >>= 1)
        sum += __shfl_down(sum, off, 64);

    __shared__ float smem[4];
    const int lane = threadIdx.x & 63;
    const int wave = threadIdx.x >> 6;
    if (lane == 0) smem[wave] = sum;
    __syncthreads();

    if (threadIdx.x == 0) {
        const float s = smem[0] + smem[1] + smem[2] + smem[3];
        const float scale = 1.0f / (Z_F * (float)N * (float)N);
        atomicAdd(out + b, s * scale);
    }
}

extern "C" void kernel_launch(void* const* d_in, const int* in_sizes, int n_in,
                              void* d_out, int out_size, void* d_ws, size_t ws_size,
                              hipStream_t stream) {
    const float* pred_rot   = (const float*)d_in[0];
    const float* pred_trans = (const float*)d_in[1];
    const float* pred_pos   = (const float*)d_in[2];
    const float* true_rot   = (const float*)d_in[3];
    const float* true_trans = (const float*)d_in[4];
    const float* true_pos   = (const float*)d_in[5];
    float* out = (float*)d_out;

    const int B = out_size;                  // 4
    const int BN = in_sizes[1] / 3;          // B*N
    const int N = BN / B;                    // 2048

    float* y = (float*)d_ws;                 // BN*8*4 B = 256 KB

    fape_pre<<<(BN + 255) / 256, 256, 0, stream>>>(pred_pos, true_pos,
                                                   y, out, BN, B);

    const int jChunks = (N + 63) / 64;       // 32
    const int fpb     = (N + 255) / 256;     // 8
    dim3 grid(fpb * jChunks, B);             // (256, 4) = 1024 blocks
    fape_main<<<grid, 256, 0, stream>>>(pred_rot, pred_trans,
                                        true_rot, true_trans,
                                        (const float4*)y, out,
                                        N, jChunks);
}

// Round 6
// 84.564 us; speedup vs baseline: 1.0682x; 1.0682x over previous
//
#include <hip/hip_runtime.h>

#define D_CLAMP2 100.0f   // D_CLAMP^2 ; min(sqrt(x),10) == sqrt(min(x,100))
#define EPS_F    1e-4f
#define Z_F      10.0f
#define JCH      64       // j atoms per block

// ---------------------------------------------------------------------------
// LANE OWNS FRAME i: its 21 constants (Rp, Rt, c) live in VGPRs for the whole
// kernel (one-time scattered loads). The j-loop reads one 6-float atom row per
// iteration at a WAVE-UNIFORM address (SALU index math, scalar-pipe loads,
// 1-2 cache lines worst case) and issues 24 VALU instrs per pair:
// 18 FMA (two 3x3 matvecs, Rt negation in free -src modifiers) + 3 norm FMA
// + min + sqrt + weighted-acc FMA. No per-lane memory in the hot loop.
// No pre-pass, no workspace: 2 dispatches total (16 B memset + this).
// ---------------------------------------------------------------------------
__global__ __launch_bounds__(256) void fape_main(
    const float* __restrict__ pred_rot,   // [B,N,3,3]
    const float* __restrict__ pred_trans, // [B,N,3]
    const float* __restrict__ pred_pos,   // [B,N,3]
    const float* __restrict__ true_rot,   // [B,N,3,3]
    const float* __restrict__ true_trans, // [B,N,3]
    const float* __restrict__ true_pos,   // [B,N,3]
    float* __restrict__ out,              // [B]
    int N, int jChunks)
{
    const int jc  = blockIdx.x % jChunks;   // 64-wide j slice
    const int fcb = blockIdx.x / jChunks;   // 256-wide i slice
    const int b   = blockIdx.y;

    const int i   = fcb * 256 + threadIdx.x;
    const float wF = (i < N) ? 1.0f : 0.0f;
    const int iv  = i < N ? i : N - 1;
    const size_t fi = (size_t)b * N + iv;

    // Per-lane frame constants -> VGPRs (one-time).
    float rp[9], rt[9];
    const float* Rp = pred_rot + fi * 9;
    const float* Rt = true_rot + fi * 9;
#pragma unroll
    for (int q = 0; q < 9; ++q) { rp[q] = Rp[q]; rt[q] = Rt[q]; }
    const float* tpv = pred_trans + fi * 3;
    const float* ttv = true_trans + fi * 3;
    const float tp0 = tpv[0], tp1 = tpv[1], tp2 = tpv[2];
    const float tt0 = ttv[0], tt1 = ttv[1], tt2 = ttv[2];
    // c[o] = Rt^T tt - Rp^T tp   (so d = Rp^T xp - Rt^T xt + c)
    float cn[3];
#pragma unroll
    for (int o = 0; o < 3; ++o) {
        cn[o] = (rt[0+o]*tt0 + rt[3+o]*tt1 + rt[6+o]*tt2)
              - (rp[0+o]*tp0 + rp[3+o]*tp1 + rp[6+o]*tp2);
    }

    const int j0 = jc * JCH;
    const float* XPb = pred_pos + (size_t)b * N * 3;   // batch base, uniform
    const float* XTb = true_pos + (size_t)b * N * 3;

    float sum = 0.0f;
#pragma unroll 8
    for (int jj = 0; jj < JCH; ++jj) {
        const int jA = j0 + jj;                         // uniform (SALU)
        const int jv = jA < N ? jA : N - 1;
        const float wj = (jA < N) ? 1.0f : 0.0f;
        const float a0 = XPb[3*jv+0], a1 = XPb[3*jv+1], a2 = XPb[3*jv+2];
        const float b0 = XTb[3*jv+0], b1 = XTb[3*jv+1], b2 = XTb[3*jv+2];

        const float d0 = fmaf(rp[0], a0, fmaf(rp[3], a1, fmaf(rp[6], a2,
                         fmaf(-rt[0], b0, fmaf(-rt[3], b1, fmaf(-rt[6], b2, cn[0]))))));
        const float d1 = fmaf(rp[1], a0, fmaf(rp[4], a1, fmaf(rp[7], a2,
                         fmaf(-rt[1], b0, fmaf(-rt[4], b1, fmaf(-rt[7], b2, cn[1]))))));
        const float d2 = fmaf(rp[2], a0, fmaf(rp[5], a1, fmaf(rp[8], a2,
                         fmaf(-rt[2], b0, fmaf(-rt[5], b1, fmaf(-rt[8], b2, cn[2]))))));
        const float s2 = fmaf(d0, d0, fmaf(d1, d1, fmaf(d2, d2, EPS_F)));
        sum = fmaf(wj, __builtin_amdgcn_sqrtf(fminf(s2, D_CLAMP2)), sum);
    }
    sum *= wF;

    // Wave (64-lane) shuffle reduction; all lanes in this block share batch b.
#pragma unroll
    for (int off = 32; off > 0; off >>= 1)
        sum += __shfl_down(sum, off, 64);

    __shared__ float smem[4];
    const int lane = threadIdx.x & 63;
    const int wave = threadIdx.x >> 6;
    if (lane == 0) smem[wave] = sum;
    __syncthreads();

    if (threadIdx.x == 0) {
        const float s = smem[0] + smem[1] + smem[2] + smem[3];
        const float scale = 1.0f / (Z_F * (float)N * (float)N);
        atomicAdd(out + b, s * scale);
    }
}

extern "C" void kernel_launch(void* const* d_in, const int* in_sizes, int n_in,
                              void* d_out, int out_size, void* d_ws, size_t ws_size,
                              hipStream_t stream) {
    const float* pred_rot   = (const float*)d_in[0];
    const float* pred_trans = (const float*)d_in[1];
    const float* pred_pos   = (const float*)d_in[2];
    const float* true_rot   = (const float*)d_in[3];
    const float* true_trans = (const float*)d_in[4];
    const float* true_pos   = (const float*)d_in[5];
    float* out = (float*)d_out;

    const int B = out_size;                  // 4
    const int BN = in_sizes[1] / 3;          // B*N
    const int N = BN / B;                    // 2048

    const int jChunks = (N + JCH - 1) / JCH; // 32
    const int iChunks = (N + 255) / 256;     // 8

    hipMemsetAsync(out, 0, (size_t)out_size * sizeof(float), stream);
    dim3 grid(iChunks * jChunks, B);         // (256, 4) = 1024 blocks
    fape_main<<<grid, 256, 0, stream>>>(pred_rot, pred_trans, pred_pos,
                                        true_rot, true_trans, true_pos,
                                        out, N, jChunks);
}

// Round 7
// 75.983 us; speedup vs baseline: 1.1888x; 1.1129x over previous
//
#include <hip/hip_runtime.h>

#define D_CLAMP2 100.0f   // D_CLAMP^2 ; min(sqrt(x),10) == sqrt(min(x,100))
#define EPS_F    1e-4f
#define Z_F      10.0f
#define JCH      64       // j atoms per block

typedef float v2f __attribute__((ext_vector_type(2)));

// ---------------------------------------------------------------------------
// LANE OWNS FRAME i (constants in VGPRs, components 0/1 packed for
// v_pk_fma_f32). The 64-atom j-slice is staged once into LDS (coalesced),
// then the hot loop does 2x ds_read_b128 at wave-uniform addresses
// (same-address broadcast) + ~17 VALU issue-slots per pair. No VMEM and no
// atomics anywhere near the hot path: blocks store partial sums to d_ws,
// a tiny reduce kernel produces out[] (deterministic, no memset needed).
// ---------------------------------------------------------------------------
__global__ __launch_bounds__(256) void fape_main(
    const float* __restrict__ pred_rot,   // [B,N,3,3]
    const float* __restrict__ pred_trans, // [B,N,3]
    const float* __restrict__ pred_pos,   // [B,N,3]
    const float* __restrict__ true_rot,   // [B,N,3,3]
    const float* __restrict__ true_trans, // [B,N,3]
    const float* __restrict__ true_pos,   // [B,N,3]
    float* __restrict__ partial,          // [B, gridDim.x]
    int N, int jChunks)
{
    const int jc  = blockIdx.x % jChunks;   // 64-wide j slice
    const int fcb = blockIdx.x / jChunks;   // 256-wide i slice
    const int b   = blockIdx.y;
    const int j0  = jc * JCH;

    // ---- Stage j-slice into LDS: row jj = {a0,a1,a2,b0 | b1,b2,pad,pad} ----
    __shared__ float4 sy[JCH * 2];
    {
        float* syf = (float*)sy;
        const float* XPb = pred_pos + (size_t)b * N * 3;
        const float* XTb = true_pos + (size_t)b * N * 3;
        for (int idx = threadIdx.x; idx < JCH * 6; idx += 256) {
            const int jj = idx / 6, c = idx - 6 * jj;
            const int jA = j0 + jj;
            const int jv = jA < N ? jA : N - 1;
            syf[jj * 8 + c] = (c < 3) ? XPb[3 * jv + c] : XTb[3 * jv + c - 3];
        }
    }

    // ---- Per-lane frame constants (one-time) ----
    const int i   = fcb * 256 + threadIdx.x;
    const float wF = (i < N) ? 1.0f : 0.0f;
    const int iv  = i < N ? i : N - 1;
    const size_t fi = (size_t)b * N + iv;

    float rp[9], rt[9];
    const float* Rp = pred_rot + fi * 9;
    const float* Rt = true_rot + fi * 9;
#pragma unroll
    for (int q = 0; q < 9; ++q) { rp[q] = Rp[q]; rt[q] = Rt[q]; }
    const float* tpv = pred_trans + fi * 3;
    const float* ttv = true_trans + fi * 3;
    const float tp0 = tpv[0], tp1 = tpv[1], tp2 = tpv[2];
    const float tt0 = ttv[0], tt1 = ttv[1], tt2 = ttv[2];
    // c[o] = Rt^T tt - Rp^T tp   (so d = Rp^T xp - Rt^T xt + c)
    float cn[3];
#pragma unroll
    for (int o = 0; o < 3; ++o) {
        cn[o] = (rt[0+o]*tt0 + rt[3+o]*tt1 + rt[6+o]*tt2)
              - (rp[0+o]*tp0 + rp[3+o]*tp1 + rp[6+o]*tp2);
    }
    // Packed columns for output components (0,1); Rt negated once here.
    const v2f RP0 = {rp[0], rp[1]}, RP1 = {rp[3], rp[4]}, RP2 = {rp[6], rp[7]};
    const v2f RN0 = {-rt[0], -rt[1]}, RN1 = {-rt[3], -rt[4]}, RN2 = {-rt[6], -rt[7]};
    const v2f CN01 = {cn[0], cn[1]};

    __syncthreads();

    float sum = 0.0f;
#pragma unroll 4
    for (int jj = 0; jj < JCH; ++jj) {
        const float4 ya = sy[2*jj + 0];     // ds_read_b128, uniform addr
        const float4 yb = sy[2*jj + 1];
        const float a0 = ya.x, a1 = ya.y, a2 = ya.z;
        const float b0 = ya.w, b1 = yb.x, b2 = yb.y;
        const float wj = (j0 + jj < N) ? 1.0f : 0.0f;

        const v2f A0 = {a0, a0}, A1 = {a1, a1}, A2 = {a2, a2};
        const v2f B0 = {b0, b0}, B1 = {b1, b1}, B2 = {b2, b2};
        const v2f d01 = __builtin_elementwise_fma(RP0, A0,
                        __builtin_elementwise_fma(RP1, A1,
                        __builtin_elementwise_fma(RP2, A2,
                        __builtin_elementwise_fma(RN0, B0,
                        __builtin_elementwise_fma(RN1, B1,
                        __builtin_elementwise_fma(RN2, B2, CN01))))));
        const float d2 = fmaf(rp[2], a0, fmaf(rp[5], a1, fmaf(rp[8], a2,
                         fmaf(-rt[2], b0, fmaf(-rt[5], b1, fmaf(-rt[8], b2, cn[2]))))));
        const float s2 = fmaf(d01.x, d01.x, fmaf(d01.y, d01.y, fmaf(d2, d2, EPS_F)));
        sum = fmaf(wj, __builtin_amdgcn_sqrtf(fminf(s2, D_CLAMP2)), sum);
    }
    sum *= wF;

    // Block reduction -> one plain store (no atomics).
#pragma unroll
    for (int off = 32; off > 0; off >>= 1)
        sum += __shfl_down(sum, off, 64);

    __shared__ float smem[4];
    const int lane = threadIdx.x & 63;
    const int wave = threadIdx.x >> 6;
    if (lane == 0) smem[wave] = sum;
    __syncthreads();
    if (threadIdx.x == 0)
        partial[(size_t)b * gridDim.x + blockIdx.x] = smem[0] + smem[1] + smem[2] + smem[3];
}

// One block per batch: deterministic tree-reduce of the partials, write out.
__global__ __launch_bounds__(256) void fape_reduce(
    const float* __restrict__ partial, float* __restrict__ out, int nPart, int N)
{
    const int b = blockIdx.x;
    float s = 0.0f;
    for (int t = threadIdx.x; t < nPart; t += 256)
        s += partial[(size_t)b * nPart + t];
#pragma unroll
    for (int off = 32; off > 0; off >>= 1)
        s += __shfl_down(s, off, 64);
    __shared__ float smem[4];
    const int lane = threadIdx.x & 63;
    const int wave = threadIdx.x >> 6;
    if (lane == 0) smem[wave] = s;
    __syncthreads();
    if (threadIdx.x == 0) {
        const float tot = smem[0] + smem[1] + smem[2] + smem[3];
        out[b] = tot / (Z_F * (float)N * (float)N);
    }
}

extern "C" void kernel_launch(void* const* d_in, const int* in_sizes, int n_in,
                              void* d_out, int out_size, void* d_ws, size_t ws_size,
                              hipStream_t stream) {
    const float* pred_rot   = (const float*)d_in[0];
    const float* pred_trans = (const float*)d_in[1];
    const float* pred_pos   = (const float*)d_in[2];
    const float* true_rot   = (const float*)d_in[3];
    const float* true_trans = (const float*)d_in[4];
    const float* true_pos   = (const float*)d_in[5];
    float* out = (float*)d_out;

    const int B = out_size;                  // 4
    const int BN = in_sizes[1] / 3;          // B*N
    const int N = BN / B;                    // 2048

    const int jChunks = (N + JCH - 1) / JCH; // 32
    const int iChunks = (N + 255) / 256;     // 8
    const int nPart   = iChunks * jChunks;   // 256

    float* partial = (float*)d_ws;           // B*nPart*4 = 4 KB

    dim3 grid(nPart, B);                     // 1024 blocks
    fape_main<<<grid, 256, 0, stream>>>(pred_rot, pred_trans, pred_pos,
                                        true_rot, true_trans, true_pos,
                                        partial, N, jChunks);
    fape_reduce<<<B, 256, 0, stream>>>(partial, out, nPart, N);
}